// Round 1
// baseline (183.856 us; speedup 1.0000x reference)
//
#include <hip/hip_runtime.h>

// VisitEncoder: out[v, :] = mean over valid codes j of logmap0(emb[ids[v,j]])
//   logmap0(x) = artanh(min(||x||, 1-1e-7)) / max(||x||,1e-15) * x   (c = 1)
//
// Layout: one wave (64 lanes) per visit. Wave is split into 4 groups of 16
// lanes; group g handles codes j = 4*it + g, each lane holding a float4
// (4 dims) of the 64-dim row -> one coalesced 256B row load per group.
// Norm reduce = 4 shuffle-xor steps within the 16-lane group.
// Final cross-group combine = shuffle-xor 16, 32. Lanes 0..15 store float4.

#define LCODES 48
#define NGROUP 4          // codes processed in parallel per iteration
#define DIM 64

__global__ __launch_bounds__(256, 4)
void visit_encoder_kernel(const int* __restrict__ ids,
                          const float* __restrict__ emb,
                          float* __restrict__ out,
                          int N) {
    const int tid  = threadIdx.x;
    const int lane = tid & 63;
    const int wave = tid >> 6;
    const int v    = blockIdx.x * 4 + wave;
    if (v >= N) return;

    // Preload this visit's 48 code ids into lanes 0..47 (one coalesced load).
    int myid = -1;
    if (lane < LCODES) myid = ids[(long)v * LCODES + lane];

    // Valid-code count for the whole visit: one ballot.
    unsigned long long valid = __ballot(myid >= 0);
    const float cnt = (float)__popcll(valid);

    const int g   = lane >> 4;   // group 0..3
    const int sub = lane & 15;   // float4 slot: dims [4*sub, 4*sub+3]

    const float4* __restrict__ emb4 = reinterpret_cast<const float4*>(emb);

    float4 acc = make_float4(0.f, 0.f, 0.f, 0.f);

    #pragma unroll
    for (int it = 0; it < LCODES / NGROUP; ++it) {
        const int j  = it * NGROUP + g;
        const int id = __shfl(myid, j, 64);   // broadcast id of code j to group g

        float4 x = make_float4(0.f, 0.f, 0.f, 0.f);
        if (id >= 0) {
            x = emb4[(long)id * (DIM / 4) + sub];   // coalesced 256B row per group
        }

        // ||x||^2 : per-lane partial then 16-lane shuffle reduce
        float ss = x.x * x.x + x.y * x.y + x.z * x.z + x.w * x.w;
        ss += __shfl_xor(ss, 1, 64);
        ss += __shfl_xor(ss, 2, 64);
        ss += __shfl_xor(ss, 4, 64);
        ss += __shfl_xor(ss, 8, 64);

        float norm = sqrtf(ss);
        norm = fmaxf(norm, 1e-15f);                 // MIN_NORM clamp
        const float arg = fminf(norm, 1.f - 1e-7f); // ATANH_EPS clamp
        // artanh(arg) = 0.5 * ln((1+arg)/(1-arg))
        const float at    = 0.5f * logf((1.f + arg) / (1.f - arg));
        const float scale = at / norm;
        // invalid code => x == 0 => contributes exactly 0 regardless of scale
        acc.x += x.x * scale;
        acc.y += x.y * scale;
        acc.z += x.z * scale;
        acc.w += x.w * scale;
    }

    // Combine the 4 groups (lanes differing in bits 4,5 hold same dims).
    acc.x += __shfl_xor(acc.x, 16, 64);
    acc.y += __shfl_xor(acc.y, 16, 64);
    acc.z += __shfl_xor(acc.z, 16, 64);
    acc.w += __shfl_xor(acc.w, 16, 64);
    acc.x += __shfl_xor(acc.x, 32, 64);
    acc.y += __shfl_xor(acc.y, 32, 64);
    acc.z += __shfl_xor(acc.z, 32, 64);
    acc.w += __shfl_xor(acc.w, 32, 64);

    if (lane < 16) {
        const float inv = 1.f / fmaxf(cnt, 1.f);
        float4 r = make_float4(acc.x * inv, acc.y * inv, acc.z * inv, acc.w * inv);
        reinterpret_cast<float4*>(out)[(long)v * (DIM / 4) + sub] = r;
    }
}

extern "C" void kernel_launch(void* const* d_in, const int* in_sizes, int n_in,
                              void* d_out, int out_size, void* d_ws, size_t ws_size,
                              hipStream_t stream) {
    const int*   ids = (const int*)d_in[0];
    const float* emb = (const float*)d_in[1];
    float*       out = (float*)d_out;

    const int N = in_sizes[0] / LCODES;       // 65536
    const int blocks = (N + 3) / 4;           // 4 waves (visits) per 256-thread block

    hipLaunchKernelGGL(visit_encoder_kernel, dim3(blocks), dim3(256), 0, stream,
                       ids, emb, out, N);
}

// Round 2
// 142.562 us; speedup vs baseline: 1.2897x; 1.2897x over previous
//
#include <hip/hip_runtime.h>

// VisitEncoder: out[v,:] = mean over valid codes j of logmap0(emb[ids[v,j]]), c=1.
//   logmap0(x) = artanh(||x||)/||x|| * x
//
// Key insight: artanh(z)/z = 1 + z^2/3 + z^4/5 + z^6/7 + O(z^8), a polynomial
// in ss = ||x||^2 -- no sqrt/log/div. Inputs are projx'd N(0,0.001) rows
// (norm ~ 0.008), so 4 terms are exact to ~1e-17 rel. A never-taken exact
// fallback guards ss > 0.04 for safety.
//
// Layout: one wave per visit, 8 lanes per code -> 8 codes/iter, 6 iters.
// Lane (g=lane>>3, s=lane&7) holds dims [4s..4s+3] and [32+4s..32+4s+3] of
// code j = 8*it+g: two coalesced 128B half-row float4 loads per group.
// Norm reduce: 3 shuffle-xor steps (1,2,4). Final combine: xor 8,16,32.

#define LCODES 48
#define DIM 64

__global__ __launch_bounds__(256, 4)
void visit_encoder_kernel(const int* __restrict__ ids,
                          const float* __restrict__ emb,
                          float* __restrict__ out,
                          int N) {
    const int tid  = threadIdx.x;
    const int lane = tid & 63;
    const int wave = tid >> 6;
    const int v    = blockIdx.x * 4 + wave;
    if (v >= N) return;

    // Preload this visit's 48 code ids into lanes 0..47 (one coalesced load).
    int myid = -1;
    if (lane < LCODES) myid = ids[(long)v * LCODES + lane];

    const unsigned long long valid = __ballot(myid >= 0);
    const float cnt = (float)__popcll(valid);

    const int g = lane >> 3;   // group 0..7: which code this lane works on
    const int s = lane & 7;    // float4 slot within each 128B half-row

    const float4* __restrict__ emb4 = reinterpret_cast<const float4*>(emb);

    float4 accA = make_float4(0.f, 0.f, 0.f, 0.f);  // dims 4s..4s+3
    float4 accB = make_float4(0.f, 0.f, 0.f, 0.f);  // dims 32+4s..32+4s+3

    #pragma unroll
    for (int it = 0; it < LCODES / 8; ++it) {
        const int j  = it * 8 + g;
        const int id = __shfl(myid, j, 64);   // broadcast code j's id to group g

        float4 a = make_float4(0.f, 0.f, 0.f, 0.f);
        float4 b = make_float4(0.f, 0.f, 0.f, 0.f);
        if (id >= 0) {
            const unsigned base = ((unsigned)id) << 4;   // id * (DIM/4)
            a = emb4[base + s];          // first 128B half: lanes 0..7 contiguous
            b = emb4[base + 8 + s];      // second 128B half
        }

        // ss = ||row||^2 : per-lane partial then 8-lane shuffle reduce
        float ss = a.x*a.x + a.y*a.y + a.z*a.z + a.w*a.w
                 + b.x*b.x + b.y*b.y + b.z*b.z + b.w*b.w;
        ss += __shfl_xor(ss, 1, 64);
        ss += __shfl_xor(ss, 2, 64);
        ss += __shfl_xor(ss, 4, 64);

        float scale;
        if (__builtin_expect(__any(ss > 0.04f), 0)) {
            // exact path (never taken for this data; keeps kernel correct always)
            const float norm = fmaxf(sqrtf(ss), 1e-15f);
            const float arg  = fminf(norm, 1.f - 1e-7f);
            scale = 0.5f * logf((1.f + arg) / (1.f - arg)) / norm;
        } else {
            // artanh(z)/z = 1 + z^2/3 + z^4/5 + z^6/7,  z^2 = ss
            scale = 1.f + ss * (0.33333333333f + ss * (0.2f + ss * 0.14285714285f));
        }

        // invalid code => a=b=0 => contributes exactly 0
        accA.x += a.x * scale;  accA.y += a.y * scale;
        accA.z += a.z * scale;  accA.w += a.w * scale;
        accB.x += b.x * scale;  accB.y += b.y * scale;
        accB.z += b.z * scale;  accB.w += b.w * scale;
    }

    // Combine the 8 groups: lanes differing in bits 3,4,5 hold the same dims.
    #pragma unroll
    for (int d = 8; d <= 32; d <<= 1) {
        accA.x += __shfl_xor(accA.x, d, 64);
        accA.y += __shfl_xor(accA.y, d, 64);
        accA.z += __shfl_xor(accA.z, d, 64);
        accA.w += __shfl_xor(accA.w, d, 64);
        accB.x += __shfl_xor(accB.x, d, 64);
        accB.y += __shfl_xor(accB.y, d, 64);
        accB.z += __shfl_xor(accB.z, d, 64);
        accB.w += __shfl_xor(accB.w, d, 64);
    }

    if (lane < 8) {
        const float inv = 1.f / fmaxf(cnt, 1.f);
        float4 rA = make_float4(accA.x * inv, accA.y * inv, accA.z * inv, accA.w * inv);
        float4 rB = make_float4(accB.x * inv, accB.y * inv, accB.z * inv, accB.w * inv);
        float4* o = reinterpret_cast<float4*>(out) + (long)v * (DIM / 4);
        o[s]     = rA;
        o[8 + s] = rB;
    }
}

extern "C" void kernel_launch(void* const* d_in, const int* in_sizes, int n_in,
                              void* d_out, int out_size, void* d_ws, size_t ws_size,
                              hipStream_t stream) {
    const int*   ids = (const int*)d_in[0];
    const float* emb = (const float*)d_in[1];
    float*       out = (float*)d_out;

    const int N = in_sizes[0] / LCODES;   // 65536
    const int blocks = (N + 3) / 4;       // 4 waves (visits) per 256-thread block

    hipLaunchKernelGGL(visit_encoder_kernel, dim3(blocks), dim3(256), 0, stream,
                       ids, emb, out, N);
}